// Round 5
// baseline (1700.244 us; speedup 1.0000x reference)
//
#include <hip/hip_runtime.h>
#include <hip/hip_bf16.h>

#define T_LEN 4096

typedef __attribute__((ext_vector_type(8))) short bfrag8;
typedef __attribute__((ext_vector_type(4))) float f32x4;

// Workgroup barrier WITHOUT vmcnt(0) drain: keeps global prefetch loads in
// flight across the barrier (the __syncthreads() lowering would drain them).
__device__ __forceinline__ void wg_barrier() {
  asm volatile("s_waitcnt lgkmcnt(0)\ns_barrier" ::: "memory");
}

__device__ __forceinline__ float fact(float x, float S, float A, float B) {
  // sigmoid: S=-1/ln2, A=0, B=1 ;  tanh: S=+2/ln2, A=1, B=-2
  float e = __builtin_amdgcn_exp2f(S * x);
  return A + B * __builtin_amdgcn_rcpf(1.0f + e);
}
__device__ __forceinline__ float ftanh(float x) {
  float e = __builtin_amdgcn_exp2f(2.8853900817779268f * x);
  return 1.0f - 2.0f * __builtin_amdgcn_rcpf(1.0f + e);
}
// Broadcast lane SEL within each aligned 4-lane group (quad_perm DPP, VALU).
template <int SEL>
__device__ __forceinline__ float qb(float v) {
  union { float f; int i; } u;
  u.f = v;
  u.i = __builtin_amdgcn_mov_dpp(u.i, SEL * 0x55, 0xF, 0xF, true);
  return u.f;
}

// ---------------------------------------------------------------------------
// Kernel 0: bf16 copy of W_enc padded to K=64 (B-operand for the encoder).
// ---------------------------------------------------------------------------
__global__ void prep_enc(const float* __restrict__ W_enc,
                         __hip_bfloat16* __restrict__ Wencb) {
  int u = threadIdx.x;
  if (u < 32) {
    for (int k = 0; k < 64; ++k)
      Wencb[u * 64 + k] = __float2bfloat16(k < 60 ? W_enc[u * 60 + k] : 0.0f);
  }
}

// ---------------------------------------------------------------------------
// Kernel 1: MFMA encoder  x[row][u] = sum_k c[row][k] * W_enc[u][k]  (bf16).
// One wave per 16 rows. Memory-bound: 251 MB read + 64 MB write.
// ---------------------------------------------------------------------------
__global__ __launch_bounds__(256) void encoder(const float* __restrict__ c,
                                               const __hip_bfloat16* __restrict__ Wencb,
                                               __hip_bfloat16* __restrict__ x) {
  const int lane = threadIdx.x & 63, wave = threadIdx.x >> 6;
  const int q = lane >> 4, l15 = lane & 15;
  const size_t r0 = ((size_t)blockIdx.x * 4 + wave) * 16;

  bfrag8 bf00 = *(const bfrag8*)(Wencb + (0 * 16 + l15) * 64 + 0 * 32 + q * 8);
  bfrag8 bf01 = *(const bfrag8*)(Wencb + (0 * 16 + l15) * 64 + 1 * 32 + q * 8);
  bfrag8 bf10 = *(const bfrag8*)(Wencb + (1 * 16 + l15) * 64 + 0 * 32 + q * 8);
  bfrag8 bf11 = *(const bfrag8*)(Wencb + (1 * 16 + l15) * 64 + 1 * 32 + q * 8);

  const float* cr = c + (r0 + l15) * 60;   // A row = l15
  float4 a0 = *(const float4*)(cr + q * 8);
  float4 a1 = *(const float4*)(cr + q * 8 + 4);
  float4 a2 = *(const float4*)(cr + 32 + q * 8);
  float4 a3 = (q == 3) ? float4{0.f, 0.f, 0.f, 0.f}
                       : *(const float4*)(cr + 36 + q * 8);
  union { bfrag8 v; __hip_bfloat16 h[8]; } A0, A1;
  A0.h[0] = __float2bfloat16(a0.x); A0.h[1] = __float2bfloat16(a0.y);
  A0.h[2] = __float2bfloat16(a0.z); A0.h[3] = __float2bfloat16(a0.w);
  A0.h[4] = __float2bfloat16(a1.x); A0.h[5] = __float2bfloat16(a1.y);
  A0.h[6] = __float2bfloat16(a1.z); A0.h[7] = __float2bfloat16(a1.w);
  A1.h[0] = __float2bfloat16(a2.x); A1.h[1] = __float2bfloat16(a2.y);
  A1.h[2] = __float2bfloat16(a2.z); A1.h[3] = __float2bfloat16(a2.w);
  A1.h[4] = __float2bfloat16(a3.x); A1.h[5] = __float2bfloat16(a3.y);
  A1.h[6] = __float2bfloat16(a3.z); A1.h[7] = __float2bfloat16(a3.w);

  f32x4 acc0 = {0.f, 0.f, 0.f, 0.f}, acc1 = {0.f, 0.f, 0.f, 0.f};
  acc0 = __builtin_amdgcn_mfma_f32_16x16x32_bf16(A0.v, bf00, acc0, 0, 0, 0);
  acc1 = __builtin_amdgcn_mfma_f32_16x16x32_bf16(A0.v, bf10, acc1, 0, 0, 0);
  acc0 = __builtin_amdgcn_mfma_f32_16x16x32_bf16(A1.v, bf01, acc0, 0, 0, 0);
  acc1 = __builtin_amdgcn_mfma_f32_16x16x32_bf16(A1.v, bf11, acc1, 0, 0, 0);

#pragma unroll
  for (int r = 0; r < 4; ++r) {  // D: col = l15, row = q*4 + r
    size_t row = r0 + q * 4 + r;
    x[row * 32 + l15]      = __float2bfloat16(acc0[r]);
    x[row * 32 + 16 + l15] = __float2bfloat16(acc1[r]);
  }
}

// ---------------------------------------------------------------------------
// Kernel 2: fused LSTM weights, K=96, GATE-PERMUTED for the 4-tile layout.
// Permuted row np = wave*64 + tile*16 + c  (wave=np>>6, tile=(np>>4)&3, c=np&15):
//   unit = wave*16 + tile*4 + (c>>2), gate = c&3, orig row no = gate*64 + unit.
// Wc[dir][np][0:32) = W_ih, [32:96) = W_hh (bf16).
// biasc[dir][np] = b[no] + W_ih[no]·b_enc  (fp32).
// ---------------------------------------------------------------------------
__global__ void prep_weights(const float* __restrict__ b_enc,
                             const float* __restrict__ W_ih_f,
                             const float* __restrict__ W_hh_f,
                             const float* __restrict__ b_f,
                             const float* __restrict__ W_ih_b,
                             const float* __restrict__ W_hh_b,
                             const float* __restrict__ b_b,
                             __hip_bfloat16* __restrict__ Wc,
                             float* __restrict__ biasc) {
  const int dir = blockIdx.x;
  const int np = threadIdx.x;
  const int w = np >> 6, tile = (np >> 4) & 3, cc = np & 15;
  const int unit = w * 16 + tile * 4 + (cc >> 2);
  const int gate = cc & 3;
  const int no = gate * 64 + unit;
  const float* W_ih = dir ? W_ih_b : W_ih_f;
  const float* W_hh = dir ? W_hh_b : W_hh_f;
  const float* bv = dir ? b_b : b_f;
  __hip_bfloat16* row = Wc + (size_t)(dir * 256 + np) * 96;
#pragma unroll
  for (int k = 0; k < 32; ++k) row[k] = __float2bfloat16(W_ih[no * 32 + k]);
#pragma unroll
  for (int j = 0; j < 64; ++j) row[32 + j] = __float2bfloat16(W_hh[no * 64 + j]);
  float bb = bv[no];
#pragma unroll
  for (int e = 0; e < 32; ++e) bb += W_ih[no * 32 + e] * b_enc[e];
  biasc[dir * 256 + np] = bb;
}

// ---------------------------------------------------------------------------
// Kernel 3: the recurrence. BATCH-2 per WG: 256 WGs = 128 pairs x 2 dirs,
// 256 thr (4 waves), 1 WG/CU -> all 256 CUs, 1 wave/SIMD.
// A rows alternate batches (row m = batch m&1) -> MFMA D reg 0 = batch 0,
// reg 1 = batch 1 in every quad: the 12 MFMAs/wave serve TWO recurrences
// (halves total MFMA FLOPs vs round 4's batch-1).
// Chained accs: acc = bias -> +x.W (regs, no wait) -> +h1 -> +h2; the two
// ds_read_b128 issue at loop top and hide under the x-MFMAs.
// Epilogue: lane owns col (tile=quad, l15) for BOTH batches -> 2 facts,
// 8 DPP gathers, redundant cell update; lanes g=0/1 write batch-0/1 h.
// One lgkm-only barrier per step.
// ---------------------------------------------------------------------------
__global__ __launch_bounds__(256) void lstm_main(
    const __hip_bfloat16* __restrict__ x, const __hip_bfloat16* __restrict__ Wc,
    const float* __restrict__ biasc, float* __restrict__ cfin) {
  __shared__ short Hbuf[2][144];  // [buf][batch*72 + unit] bf16 (stride 72: <=2-way)

  const int tid = threadIdx.x, lane = tid & 63, wave = tid >> 6;
  const int quad = lane >> 4, l15 = lane & 15;
  const int g = lane & 3;
  const int unit = wave * 16 + quad * 4 + (l15 >> 2);
  const int dir = (int)blockIdx.x & 1;
  const int b0 = ((int)blockIdx.x >> 1) << 1;

  // loop-invariant weight fragments (B-operand: lane = col, k = quad*8+j)
  bfrag8 wf[4][3];
  float bias[4];
#pragma unroll
  for (int tl = 0; tl < 4; ++tl) {
    const int np = wave * 64 + tl * 16 + l15;
    const __hip_bfloat16* wr = Wc + (size_t)(dir * 256 + np) * 96 + quad * 8;
#pragma unroll
    for (int kt = 0; kt < 3; ++kt) wf[tl][kt] = *(const bfrag8*)(wr + kt * 32);
    bias[tl] = biasc[dir * 256 + np];
  }

  // activation constants for my gate column (g==2 is the tanh gate)
  const bool isg = (g == 2);
  const float S = isg ? 2.8853900817779268f : -1.4426950408889634f;
  const float Aa = isg ? 1.0f : 0.0f;
  const float Bb = isg ? -2.0f : 1.0f;

  // A row = l15 -> batch l15&1; x frag: K = quad*8..+7
  const __hip_bfloat16* xr = x + (size_t)(b0 + (l15 & 1)) * T_LEN * 32 + quad * 8;
  const int hrd = (l15 & 1) * 72 + quad * 8;  // h A-frag read base (shorts)

  if (tid < 288) ((short*)Hbuf)[tid] = 0;  // h0 = 0 (both buffers)

  bfrag8 xb[4];
#pragma unroll
  for (int qq = 0; qq < 4; ++qq) {  // prefetch x frags for t = 0..3
    int tp = dir ? (T_LEN - 1 - qq) : qq;
    xb[qq] = *(const bfrag8*)(xr + (size_t)tp * 32);
  }

  float cst0 = 0.f, cst1 = 0.f;
  wg_barrier();

#pragma unroll 4
  for (int t = 0; t < T_LEN; ++t) {
    const int cur = t & 1;
    // h A-frags from LDS ping-pong (issued first; latency hides under x-MFMAs)
    bfrag8 ahA = *(const bfrag8*)&Hbuf[cur][hrd];        // h units  q*8..q*8+7
    bfrag8 ahB = *(const bfrag8*)&Hbuf[cur][hrd + 32];   // h units 32+q*8..
    // ---- chained MFMAs: bias -> x (regs) -> h1 -> h2, 4 independent chains
    f32x4 a0 = {bias[0], bias[0], bias[0], bias[0]};
    f32x4 a1 = {bias[1], bias[1], bias[1], bias[1]};
    f32x4 a2 = {bias[2], bias[2], bias[2], bias[2]};
    f32x4 a3 = {bias[3], bias[3], bias[3], bias[3]};
    a0 = __builtin_amdgcn_mfma_f32_16x16x32_bf16(xb[t & 3], wf[0][0], a0, 0, 0, 0);
    a1 = __builtin_amdgcn_mfma_f32_16x16x32_bf16(xb[t & 3], wf[1][0], a1, 0, 0, 0);
    a2 = __builtin_amdgcn_mfma_f32_16x16x32_bf16(xb[t & 3], wf[2][0], a2, 0, 0, 0);
    a3 = __builtin_amdgcn_mfma_f32_16x16x32_bf16(xb[t & 3], wf[3][0], a3, 0, 0, 0);
    a0 = __builtin_amdgcn_mfma_f32_16x16x32_bf16(ahA, wf[0][1], a0, 0, 0, 0);
    a1 = __builtin_amdgcn_mfma_f32_16x16x32_bf16(ahA, wf[1][1], a1, 0, 0, 0);
    a2 = __builtin_amdgcn_mfma_f32_16x16x32_bf16(ahA, wf[2][1], a2, 0, 0, 0);
    a3 = __builtin_amdgcn_mfma_f32_16x16x32_bf16(ahA, wf[3][1], a3, 0, 0, 0);
    a0 = __builtin_amdgcn_mfma_f32_16x16x32_bf16(ahB, wf[0][2], a0, 0, 0, 0);
    a1 = __builtin_amdgcn_mfma_f32_16x16x32_bf16(ahB, wf[1][2], a1, 0, 0, 0);
    a2 = __builtin_amdgcn_mfma_f32_16x16x32_bf16(ahB, wf[2][2], a2, 0, 0, 0);
    a3 = __builtin_amdgcn_mfma_f32_16x16x32_bf16(ahB, wf[3][2], a3, 0, 0, 0);
    {  // prefetch x frag for t+4 (stays in flight across the lgkm barrier)
      int tn = t + 4; if (tn > T_LEN - 1) tn = T_LEN - 1;
      int tp = dir ? (T_LEN - 1 - tn) : tn;
      xb[t & 3] = *(const bfrag8*)(xr + (size_t)tp * 32);
    }
    // ---- my gate value, both batches: tile = quad; reg 0/1 = batch 0/1 ----
    float v0 = (quad & 2) ? ((quad & 1) ? a3[0] : a2[0]) : ((quad & 1) ? a1[0] : a0[0]);
    float v1 = (quad & 2) ? ((quad & 1) ? a3[1] : a2[1]) : ((quad & 1) ? a1[1] : a0[1]);
    float av0 = fact(v0, S, Aa, Bb);
    float av1 = fact(v1, S, Aa, Bb);
    // gather the 4 gates of my unit from my aligned 4-lane group (i,f,g,o)
    float i0 = qb<0>(av0), f0 = qb<1>(av0), g0v = qb<2>(av0), o0 = qb<3>(av0);
    float i1 = qb<0>(av1), f1 = qb<1>(av1), g1v = qb<2>(av1), o1 = qb<3>(av1);
    cst0 = f0 * cst0 + i0 * g0v;
    cst1 = f1 * cst1 + i1 * g1v;
    float h0 = o0 * ftanh(cst0);
    float h1 = o1 * ftanh(cst1);
    short* hb = Hbuf[cur ^ 1];
    if (g == 0) *(__hip_bfloat16*)&hb[unit] = __float2bfloat16(h0);       // batch 0
    if (g == 1) *(__hip_bfloat16*)&hb[72 + unit] = __float2bfloat16(h1);  // batch 1
    wg_barrier();
  }

  if (g < 2) {  // reference quirk: final CELL state feeds the FC
    cfin[(size_t)(dir * 256 + b0 + g) * 64 + unit] = g ? cst1 : cst0;
  }
}

// ---------------------------------------------------------------------------
// Kernel 4: out[b,:] = [c_fwd(b) ; c_bwd(b)] @ W_fin^T + b_fin
// ---------------------------------------------------------------------------
__global__ void final_fc(const float* __restrict__ cfin,
                         const float* __restrict__ W_fin,
                         const float* __restrict__ b_fin,
                         float* __restrict__ out) {
  int b = threadIdx.x;  // 256 threads, 1 block
  const float* cf = cfin + (size_t)b * 64;
  const float* cb = cfin + (size_t)(256 + b) * 64;
  float a0 = b_fin[0], a1 = b_fin[1], a2 = b_fin[2];
  for (int u = 0; u < 64; ++u) {
    float vf = cf[u], vb = cb[u];
    a0 += W_fin[0 * 128 + u] * vf + W_fin[0 * 128 + 64 + u] * vb;
    a1 += W_fin[1 * 128 + u] * vf + W_fin[1 * 128 + 64 + u] * vb;
    a2 += W_fin[2 * 128 + u] * vf + W_fin[2 * 128 + 64 + u] * vb;
  }
  out[b * 3 + 0] = a0;
  out[b * 3 + 1] = a1;
  out[b * 3 + 2] = a2;
}

extern "C" void kernel_launch(void* const* d_in, const int* in_sizes, int n_in,
                              void* d_out, int out_size, void* d_ws, size_t ws_size,
                              hipStream_t stream) {
  (void)in_sizes; (void)n_in; (void)out_size; (void)ws_size;
  const float* c      = (const float*)d_in[0];
  const float* W_enc  = (const float*)d_in[1];
  const float* b_enc  = (const float*)d_in[2];
  const float* W_ih_f = (const float*)d_in[3];
  const float* W_hh_f = (const float*)d_in[4];
  const float* b_f    = (const float*)d_in[5];
  const float* W_ih_b = (const float*)d_in[6];
  const float* W_hh_b = (const float*)d_in[7];
  const float* b_b    = (const float*)d_in[8];
  const float* W_fin  = (const float*)d_in[9];
  const float* b_fin  = (const float*)d_in[10];
  float* out = (float*)d_out;

  char* ws = (char*)d_ws;
  __hip_bfloat16* x     = (__hip_bfloat16*)ws;                      // 64 MiB
  __hip_bfloat16* Wc    = (__hip_bfloat16*)(ws + 67108864);         // 98304 B
  float* biasc          = (float*)(ws + 67108864 + 98304);          // 2048 B
  __hip_bfloat16* Wencb = (__hip_bfloat16*)(ws + 67108864 + 100352); // 4096 B
  float* cfin           = (float*)(ws + 67108864 + 104448);         // 131072 B

  prep_enc<<<1, 32, 0, stream>>>(W_enc, Wencb);
  prep_weights<<<2, 256, 0, stream>>>(b_enc, W_ih_f, W_hh_f, b_f,
                                      W_ih_b, W_hh_b, b_b, Wc, biasc);
  encoder<<<16384, 256, 0, stream>>>(c, Wencb, x);
  lstm_main<<<256, 256, 0, stream>>>(x, Wc, biasc, cfin);
  final_fc<<<1, 256, 0, stream>>>(cfin, W_fin, b_fin, out);
}